// Round 5
// baseline (2441.761 us; speedup 1.0000x reference)
//
#include <hip/hip_runtime.h>

#define N_ITER 20
#define ALPHA 0.01f

typedef unsigned short ushort_t;
typedef __attribute__((ext_vector_type(8))) short bf16x8;
typedef __attribute__((ext_vector_type(16))) float f32x16;

__device__ __forceinline__ float csign(int a, int b) {
    int s = 0;
    for (int aa = a >> 1; aa; aa >>= 1) s += __popc(aa & b);
    return (s & 1) ? -1.0f : 1.0f;
}

__device__ __forceinline__ float revsign(int b) {
    int k = __popc(b);
    return ((k * (k - 1) / 2) & 1) ? -1.0f : 1.0f;
}

__device__ __forceinline__ ushort_t f2bf(float f) {
    union { float f; unsigned u; } v;
    v.f = f;
    unsigned r = v.u + 0x7fffu + ((v.u >> 16) & 1u);  // RNE; inputs finite
    return (ushort_t)(r >> 16);
}

__device__ __forceinline__ float bf2f(ushort_t u) {
    union { unsigned u; float f; } v;
    v.u = ((unsigned)u) << 16;
    return v.f;
}

// Swizzled storage for logical (r, k) in an [R][K] bf16 GEMM-operand buffer.
// Within each 32-element k-group (64 B), 16B block j lives at j ^ (r&3).
// Any 32-elem-aligned span is a permuted contiguous 64 B -> verbatim LDS staging;
// ds_read_b128 fragment reads then hit every bank exactly 8x per wave (conflict-free).
__device__ __forceinline__ size_t swz2(int r, int k, int K) {
    return (size_t)r * K + (k & ~31) + ((((k >> 3) ^ r) & 3) << 3) + (k & 7);
}

__device__ __forceinline__ void async16(const void* g, void* l) {
    __builtin_amdgcn_global_load_lds((const __attribute__((address_space(1))) void*)g,
                                     (__attribute__((address_space(3))) void*)l, 16, 0, 0);
}

// Build bf16 swizzled B^T ("[N][K]") GP matrices from W [P, Q, 8]
__global__ void build_M_kernel(const float* __restrict__ W, ushort_t* __restrict__ Mfbt,
                               ushort_t* __restrict__ Mrbt, int P, int Q) {
    int idx = blockIdx.x * blockDim.x + threadIdx.x;
    int total = P * Q * 64;
    if (idx >= total) return;
    int c = idx & 7;
    int a = (idx >> 3) & 7;
    int pq = idx >> 6;
    int q = pq % Q;
    int p = pq / Q;
    int b = a ^ c;
    float w = W[((size_t)p * Q + q) * 8 + b];
    float s = csign(a, b);
    Mfbt[swz2(p * 8 + c, q * 8 + a, Q * 8)] = f2bf(s * w);
    Mrbt[swz2(q * 8 + c, p * 8 + a, P * 8)] = f2bf(s * revsign(b) * w);
}

// fp32 [R][K] plain -> bf16 swizzled
__global__ void f2bf_swz_kernel(const float* __restrict__ in, ushort_t* __restrict__ out,
                                int n, int kshift) {
    int i = blockIdx.x * blockDim.x + threadIdx.x;
    if (i >= n) return;
    int K = 1 << kshift;
    int r = i >> kshift;
    int k = i & (K - 1);
    out[swz2(r, k, K)] = f2bf(in[i]);
}

// MFMA bf16 GEMM body: BMxBN block, BK=32 double-buffered, 256 threads (4 waves 2x2),
// wave tile (BM/2)x(BN/2) via 32x32x16 MFMA (FI x FJ fragments).
// A [M,K] bf16 swz2, BT [N,K] bf16 swz2.
// MODE 0: Bout bf16 plain = bf16(A@B)
// MODE 1: Bout bf16 swz   = bf16(X - A@B)
// MODE 2: h=X; p=Pb; g=clip(-acc+h-p); hn=h-a*g; Hout=hn; Bout=swz(hn); B2out=swz(hn-p)
// MODE 3: h=X; g=clip(-acc);           hn=h-a*g; Hout=hn; Bout=swz(hn)
template <int MODE, int BM, int BN>
__device__ __forceinline__ void gemm_body(ushort_t* __restrict__ S,
                                          const ushort_t* __restrict__ A,
                                          const ushort_t* __restrict__ BT,
                                          const float* __restrict__ X,
                                          const ushort_t* __restrict__ Pb,
                                          float* __restrict__ Hout,
                                          ushort_t* __restrict__ Bout,
                                          ushort_t* __restrict__ B2out,
                                          int K, int N, int bx, int by) {
    constexpr int FI = BM / 64;
    constexpr int FJ = BN / 64;
    constexpr int SBUF = (BM + BN) * 32;  // elems per LDS buffer
    constexpr int CPW = (BM + BN) / 64;   // 1KB chunks per wave

    const int t = threadIdx.x;
    const int lane = t & 63;
    const int w = t >> 6;
    const int wr = w >> 1;
    const int wc = w & 1;
    const int l31 = lane & 31;
    const int lh = lane >> 5;       // k-octet selector
    const int p0 = lh ^ (lane & 3); // swizzled 16B-block position, k-step 0
    const int row0 = by * BM;
    const int col0 = bx * BN;

    // staging: 1KB chunk = 16 rows x 32 elems; lane l -> row l/4, elems (l%4)*8
    const int srow = lane >> 2;
    const int sk8 = (lane & 3) * 8;
    const ushort_t* gp[CPW];
    int lofs[CPW];
#pragma unroll
    for (int cc = 0; cc < CPW; ++cc) {
        int ch = cc * 4 + w;
        if (ch * 16 < BM) {
            gp[cc] = A + (size_t)(row0 + ch * 16 + srow) * K + sk8;
        } else {
            gp[cc] = BT + (size_t)(col0 + ch * 16 - BM + srow) * K + sk8;
        }
        lofs[cc] = ch * 512;
    }

    f32x16 acc[FI][FJ];
#pragma unroll
    for (int i = 0; i < FI; ++i)
#pragma unroll
        for (int j = 0; j < FJ; ++j)
#pragma unroll
            for (int r = 0; r < 16; ++r) acc[i][j][r] = 0.0f;

    const int T = K >> 5;
#pragma unroll
    for (int cc = 0; cc < CPW; ++cc) {
        async16(gp[cc], &S[lofs[cc]]);
        gp[cc] += 32;
    }
    __syncthreads();

    for (int tt = 0; tt < T; ++tt) {
        const ushort_t* cur = S + (tt & 1) * SBUF;
        bf16x8 af[2][FI], bfm[2][FJ];
#pragma unroll
        for (int s = 0; s < 2; ++s) {
            int p = (s ? (p0 ^ 2) : p0) * 8;
#pragma unroll
            for (int i = 0; i < FI; ++i)
                af[s][i] = *(const bf16x8*)&cur[(wr * (BM / 2) + i * 32 + l31) * 32 + p];
#pragma unroll
            for (int j = 0; j < FJ; ++j)
                bfm[s][j] = *(const bf16x8*)&cur[(BM + wc * (BN / 2) + j * 32 + l31) * 32 + p];
        }
        if (tt + 1 < T) {
            ushort_t* nxt = S + ((tt + 1) & 1) * SBUF;
#pragma unroll
            for (int cc = 0; cc < CPW; ++cc) {
                async16(gp[cc], &nxt[lofs[cc]]);
                gp[cc] += 32;
            }
        }
#pragma unroll
        for (int s = 0; s < 2; ++s)
#pragma unroll
            for (int i = 0; i < FI; ++i)
#pragma unroll
                for (int j = 0; j < FJ; ++j)
                    acc[i][j] = __builtin_amdgcn_mfma_f32_32x32x16_bf16(af[s][i], bfm[s][j],
                                                                        acc[i][j], 0, 0, 0);
        __syncthreads();
    }

    // epilogue: C/D layout col=lane&31, row=(reg&3)+8*(reg>>2)+4*(lane>>5)
#pragma unroll
    for (int i = 0; i < FI; ++i) {
#pragma unroll
        for (int j = 0; j < FJ; ++j) {
#pragma unroll
            for (int r = 0; r < 16; ++r) {
                int row = row0 + wr * (BM / 2) + i * 32 + (r & 3) + 8 * (r >> 2) + 4 * lh;
                int col = col0 + wc * (BN / 2) + j * 32 + l31;
                size_t off = (size_t)row * N + col;
                float v = acc[i][j][r];
                if (MODE == 0) {
                    Bout[off] = f2bf(v);
                } else if (MODE == 1) {
                    Bout[swz2(row, col, N)] = f2bf(X[off] - v);
                } else if (MODE == 2) {
                    float h = X[off];
                    float p = bf2f(Pb[off]);
                    float g = fminf(fmaxf(-v + h - p, -1.0f), 1.0f);
                    float hn = h - ALPHA * g;
                    Hout[off] = hn;
                    size_t so = swz2(row, col, N);
                    Bout[so] = f2bf(hn);
                    B2out[so] = f2bf(hn - p);
                } else {
                    float h = X[off];
                    float g = fminf(fmaxf(-v, -1.0f), 1.0f);
                    float hn = h - ALPHA * g;
                    Hout[off] = hn;
                    Bout[swz2(row, col, N)] = f2bf(hn);
                }
            }
        }
    }
}

// Fused G1+G2: blocks [0,512) do E1b = swz(bf16(X - H1b@M1)) [4096x2048,K=1024];
// blocks [512,768) do P2b = bf16(H2b@M2) plain [4096x1024,K=512]. Both 128x128.
__global__ __launch_bounds__(256, 3) void g12_kernel(
    const ushort_t* __restrict__ H1b, const ushort_t* __restrict__ M1bt,
    const float* __restrict__ X, ushort_t* __restrict__ E1b,
    const ushort_t* __restrict__ H2b, const ushort_t* __restrict__ M2bt,
    ushort_t* __restrict__ P2b) {
    __shared__ ushort_t S[2 * 256 * 32];
    int bid = blockIdx.x;
    if (bid < 512) {
        gemm_body<1, 128, 128>(S, H1b, M1bt, X, nullptr, nullptr, E1b, nullptr,
                               1024, 2048, bid & 15, bid >> 4);
    } else {
        int b2 = bid - 512;
        gemm_body<0, 128, 128>(S, H2b, M2bt, nullptr, nullptr, nullptr, P2b, nullptr,
                               512, 1024, b2 & 7, b2 >> 3);
    }
}

// G3: H1 update, 128x64 blocks, K=2048, N=1024
__global__ __launch_bounds__(256, 3) void g3_kernel(
    const ushort_t* __restrict__ E1b, const ushort_t* __restrict__ M1rbt,
    const float* __restrict__ H1, const ushort_t* __restrict__ P2b,
    float* __restrict__ H1out, ushort_t* __restrict__ H1b, ushort_t* __restrict__ E2b) {
    __shared__ ushort_t S[2 * 192 * 32];
    gemm_body<2, 128, 64>(S, E1b, M1rbt, H1, P2b, H1out, H1b, E2b,
                          2048, 1024, blockIdx.x, blockIdx.y);
}

// G4: H2 update, 128x64 blocks, K=1024, N=512
__global__ __launch_bounds__(256, 3) void g4_kernel(
    const ushort_t* __restrict__ E2b, const ushort_t* __restrict__ M2rbt,
    const float* __restrict__ H2, float* __restrict__ H2out, ushort_t* __restrict__ H2b) {
    __shared__ ushort_t S[2 * 192 * 32];
    gemm_body<3, 128, 64>(S, E2b, M2rbt, H2, nullptr, H2out, H2b, nullptr,
                          1024, 512, blockIdx.x, blockIdx.y);
}

extern "C" void kernel_launch(void* const* d_in, const int* in_sizes, int n_in,
                              void* d_out, int out_size, void* d_ws, size_t ws_size,
                              hipStream_t stream) {
    const float* X  = (const float*)d_in[0];  // [4096, 256, 8]
    const float* W1 = (const float*)d_in[1];  // [256, 128, 8]
    const float* W2 = (const float*)d_in[2];  // [128, 64, 8]
    const float* h1 = (const float*)d_in[3];  // [4096, 128, 8]
    const float* h2 = (const float*)d_in[4];  // [4096, 64, 8]
    float* out = (float*)d_out;

    const size_t szX  = (size_t)4096 * 2048;
    const size_t szH1 = (size_t)4096 * 1024;
    const size_t szH2 = (size_t)4096 * 512;

    float* outX = out;
    float* H1 = out + szX;
    float* H2 = H1 + szH1;

    // E buffers (bf16, swz2) live in the x output region; x copied in at the end.
    ushort_t* E1b = (ushort_t*)outX;              // [4096, 2048] bf16 = 16 MB
    ushort_t* E2b = (ushort_t*)(outX + szX / 2);  // [4096, 1024] bf16 = 8 MB

    // workspace: 4+4+1+1+8+8+4 = 30 MB
    ushort_t* M1bt  = (ushort_t*)d_ws;             // [2048, 1024] swz2
    ushort_t* M1rbt = M1bt + (size_t)2048 * 1024;  // [1024, 2048] swz2
    ushort_t* M2bt  = M1rbt + (size_t)1024 * 2048; // [1024, 512]  swz2
    ushort_t* M2rbt = M2bt + (size_t)1024 * 512;   // [512, 1024]  swz2
    ushort_t* P2b   = M2rbt + (size_t)512 * 1024;  // [4096, 1024] plain bf16
    ushort_t* H1b   = P2b + szH1;                  // [4096, 1024] swz2
    ushort_t* H2b   = H1b + szH1;                  // [4096, 512]  swz2

    build_M_kernel<<<(256 * 128 * 64 + 255) / 256, 256, 0, stream>>>(W1, M1bt, M1rbt, 256, 128);
    build_M_kernel<<<(128 * 64 * 64 + 255) / 256, 256, 0, stream>>>(W2, M2bt, M2rbt, 128, 64);

    hipMemcpyAsync(H1, h1, szH1 * sizeof(float), hipMemcpyDeviceToDevice, stream);
    hipMemcpyAsync(H2, h2, szH2 * sizeof(float), hipMemcpyDeviceToDevice, stream);
    f2bf_swz_kernel<<<(int)((szH1 + 255) / 256), 256, 0, stream>>>(h1, H1b, (int)szH1, 10);
    f2bf_swz_kernel<<<(int)((szH2 + 255) / 256), 256, 0, stream>>>(h2, H2b, (int)szH2, 9);

    for (int it = 0; it < N_ITER; ++it) {
        g12_kernel<<<768, 256, 0, stream>>>(H1b, M1bt, X, E1b, H2b, M2bt, P2b);
        g3_kernel<<<dim3(1024 / 64, 4096 / 128), 256, 0, stream>>>(E1b, M1rbt, H1, P2b,
                                                                   H1, H1b, E2b);
        g4_kernel<<<dim3(512 / 64, 4096 / 128), 256, 0, stream>>>(E2b, M2rbt, H2, H2, H2b);
    }

    // x passes through unchanged; written last since its region held E1b/E2b
    hipMemcpyAsync(outX, X, szX * sizeof(float), hipMemcpyDeviceToDevice, stream);
}

// Round 6
// 1330.013 us; speedup vs baseline: 1.8359x; 1.8359x over previous
//
#include <hip/hip_runtime.h>

#define N_ITER 20
#define ALPHA 0.01f

typedef unsigned short ushort_t;
typedef __attribute__((ext_vector_type(8))) short bf16x8;
typedef __attribute__((ext_vector_type(16))) float f32x16;

__device__ __forceinline__ float csign(int a, int b) {
    int s = 0;
    for (int aa = a >> 1; aa; aa >>= 1) s += __popc(aa & b);
    return (s & 1) ? -1.0f : 1.0f;
}

__device__ __forceinline__ float revsign(int b) {
    int k = __popc(b);
    return ((k * (k - 1) / 2) & 1) ? -1.0f : 1.0f;
}

__device__ __forceinline__ ushort_t f2bf(float f) {
    union { float f; unsigned u; } v;
    v.f = f;
    unsigned r = v.u + 0x7fffu + ((v.u >> 16) & 1u);  // RNE; inputs finite
    return (ushort_t)(r >> 16);
}

__device__ __forceinline__ float bf2f(ushort_t u) {
    union { unsigned u; float f; } v;
    v.u = ((unsigned)u) << 16;
    return v.f;
}

// Swizzled storage for logical (r, k) in an [R][K] bf16 operand buffer.
// Within each 64-elem k-group (128 B = one full LDS bank line set), 8-elem
// 16B block j lives at position j ^ (r&7). Verbatim LDS staging; fragment
// reads hit all 32 banks with 2-way (free) aliasing per 16-lane group.
__device__ __forceinline__ size_t swz64(int r, int k, int K) {
    return (size_t)r * K + (k & ~63) + ((((k >> 3) ^ r) & 7) << 3) + (k & 7);
}

__device__ __forceinline__ void async16(const void* g, void* l) {
    __builtin_amdgcn_global_load_lds((const __attribute__((address_space(1))) void*)g,
                                     (__attribute__((address_space(3))) void*)l, 16, 0, 0);
}

// Build bf16 swz64 GP matrices from W [P, Q, 8]:
//  MfA  [Q8][P8]: forward GP as A-layout   MfA[q8+a][p8+c]  = s*w
//  Mrbt [Q8][P8]: reverse GP as B^T layout Mrbt[q8+c][p8+a] = s*rev(b)*w
//  Mrneg: -Mrbt;  Mbt [P8][Q8]: forward GP as B^T layout Mbt[p8+c][q8+a] = s*w
__global__ void build_M_kernel(const float* __restrict__ W, ushort_t* __restrict__ MfA,
                               ushort_t* __restrict__ Mrbt, ushort_t* __restrict__ Mrneg,
                               ushort_t* __restrict__ Mbt, int P, int Q) {
    int idx = blockIdx.x * blockDim.x + threadIdx.x;
    int total = P * Q * 64;
    if (idx >= total) return;
    int c = idx & 7;
    int a = (idx >> 3) & 7;
    int pq = idx >> 6;
    int q = pq % Q;
    int p = pq / Q;
    int b = a ^ c;
    float w = W[((size_t)p * Q + q) * 8 + b];
    float fw = csign(a, b) * w;
    float rw = csign(a, b) * revsign(b) * w;
    MfA[swz64(q * 8 + a, p * 8 + c, P * 8)] = f2bf(fw);
    Mrbt[swz64(q * 8 + c, p * 8 + a, P * 8)] = f2bf(rw);
    if (Mrneg) Mrneg[swz64(q * 8 + c, p * 8 + a, P * 8)] = f2bf(-rw);
    if (Mbt) Mbt[swz64(p * 8 + c, q * 8 + a, Q * 8)] = f2bf(fw);
}

// fp32 [R][K] plain -> bf16 swz64
__global__ void f2bf_swz_kernel(const float* __restrict__ in, ushort_t* __restrict__ out,
                                int n, int kshift) {
    int i = blockIdx.x * blockDim.x + threadIdx.x;
    if (i >= n) return;
    int K = 1 << kshift;
    int r = i >> kshift;
    int k = i & (K - 1);
    out[swz64(r, k, K)] = f2bf(in[i]);
}

// MFMA bf16 GEMM body. BMxBN block, BK=64, single LDS buffer (m97 2-barrier loop),
// 256 threads = 4 waves 2x2, wave tile (BM/2)x(BN/2) of 32x32x16 MFMAs.
// Optional second phase (A2,BT2,K2) accumulates into the same acc.
// MODE 0: Bout bf16 plain = bf16(acc)                       (P2b)
// MODE 1: Fout fp32 plain = acc                             (R precompute)
// MODE 2: g=clip(acc - Rf - P2b); hn=Xf - a*g; Hout=hn fp32; Bout=swz64(hn)
// MODE 3: g=clip(acc);            hn=Xf - a*g; Hout=hn fp32; Bout=swz64(hn)
// MODE 4: Bout[swz64(col,row,N)] = bf16(acc + (ADDI && row==col))   (GmT build; M==N)
template <int MODE, int BM, int BN, bool ADDI>
__device__ __forceinline__ void gemm_body(ushort_t* __restrict__ S,
                                          const ushort_t* __restrict__ A,
                                          const ushort_t* __restrict__ BT, int K,
                                          const ushort_t* __restrict__ A2,
                                          const ushort_t* __restrict__ BT2, int K2,
                                          const float* __restrict__ Xf,
                                          const ushort_t* __restrict__ Pb,
                                          const float* __restrict__ Rf,
                                          float* __restrict__ Hout,
                                          ushort_t* __restrict__ Bout,
                                          float* __restrict__ Fout,
                                          int N, int bx, int by) {
    constexpr int FI = BM / 64;
    constexpr int FJ = BN / 64;
    constexpr int CPW = (BM + BN) / 32;  // 1KB chunks (8 rows x 64 elems) per wave

    const int t = threadIdx.x;
    const int lane = t & 63;
    const int w = t >> 6;
    const int wr = w >> 1;
    const int wc = w & 1;
    const int l31 = lane & 31;
    const int lh = lane >> 5;
    const int row0 = by * BM;
    const int col0 = bx * BN;
    const int srow = lane >> 3;
    const int sk = (lane & 7) * 8;
    const int sw7 = l31 & 7;

    f32x16 acc[FI][FJ];
#pragma unroll
    for (int i = 0; i < FI; ++i)
#pragma unroll
        for (int j = 0; j < FJ; ++j)
#pragma unroll
            for (int r = 0; r < 16; ++r) acc[i][j][r] = 0.0f;

    for (int ph = 0; ph < 2; ++ph) {
        const ushort_t* Ap = ph ? A2 : A;
        const ushort_t* Bp = ph ? BT2 : BT;
        const int Kp = ph ? K2 : K;
        if (Kp == 0) break;

        const ushort_t* gp[CPW];
        int lofs[CPW];
#pragma unroll
        for (int cc = 0; cc < CPW; ++cc) {
            int ch = cc * 4 + w;
            int r8 = ch * 8;
            if (r8 < BM) {
                gp[cc] = Ap + (size_t)(row0 + r8 + srow) * Kp + sk;
            } else {
                gp[cc] = Bp + (size_t)(col0 + r8 - BM + srow) * Kp + sk;
            }
            lofs[cc] = ch * 512;
        }

        const int T = Kp >> 6;
        for (int tt = 0; tt < T; ++tt) {
#pragma unroll
            for (int cc = 0; cc < CPW; ++cc) {
                async16(gp[cc], &S[lofs[cc]]);
                gp[cc] += 64;
            }
            __syncthreads();
            bf16x8 af[4][FI], bfm[4][FJ];
#pragma unroll
            for (int s = 0; s < 4; ++s) {
                int pos = ((2 * s + lh) ^ sw7) * 8;
#pragma unroll
                for (int i = 0; i < FI; ++i)
                    af[s][i] = *(const bf16x8*)&S[(wr * (BM / 2) + i * 32 + l31) * 64 + pos];
#pragma unroll
                for (int j = 0; j < FJ; ++j)
                    bfm[s][j] = *(const bf16x8*)&S[(BM + wc * (BN / 2) + j * 32 + l31) * 64 + pos];
            }
#pragma unroll
            for (int s = 0; s < 4; ++s)
#pragma unroll
                for (int i = 0; i < FI; ++i)
#pragma unroll
                    for (int j = 0; j < FJ; ++j)
                        acc[i][j] = __builtin_amdgcn_mfma_f32_32x32x16_bf16(af[s][i], bfm[s][j],
                                                                            acc[i][j], 0, 0, 0);
            __syncthreads();
        }
    }

    // epilogue: C/D layout col=lane&31, row=(reg&3)+8*(reg>>2)+4*(lane>>5)
#pragma unroll
    for (int i = 0; i < FI; ++i) {
#pragma unroll
        for (int j = 0; j < FJ; ++j) {
#pragma unroll
            for (int r = 0; r < 16; ++r) {
                int row = row0 + wr * (BM / 2) + i * 32 + (r & 3) + 8 * (r >> 2) + 4 * lh;
                int col = col0 + wc * (BN / 2) + j * 32 + l31;
                size_t off = (size_t)row * N + col;
                float v = acc[i][j][r];
                if (MODE == 0) {
                    Bout[off] = f2bf(v);
                } else if (MODE == 1) {
                    Fout[off] = v;
                } else if (MODE == 2) {
                    float h = Xf[off];
                    float g = fminf(fmaxf(v - Rf[off] - bf2f(Pb[off]), -1.0f), 1.0f);
                    float hn = h - ALPHA * g;
                    Hout[off] = hn;
                    Bout[swz64(row, col, N)] = f2bf(hn);
                } else if (MODE == 3) {
                    float h = Xf[off];
                    float g = fminf(fmaxf(v, -1.0f), 1.0f);
                    float hn = h - ALPHA * g;
                    Hout[off] = hn;
                    Bout[swz64(row, col, N)] = f2bf(hn);
                } else {  // MODE 4 (square M==N)
                    float vv = v + ((ADDI && row == col) ? 1.0f : 0.0f);
                    Bout[swz64(col, row, N)] = f2bf(vv);
                }
            }
        }
    }
}

template <int MODE, int BM, int BN, bool ADDI>
__global__ __launch_bounds__(256) void gemm_k(const ushort_t* __restrict__ A,
                                              const ushort_t* __restrict__ BT, int K,
                                              const ushort_t* __restrict__ A2,
                                              const ushort_t* __restrict__ BT2, int K2,
                                              const float* __restrict__ Xf,
                                              const ushort_t* __restrict__ Pb,
                                              const float* __restrict__ Rf,
                                              float* __restrict__ Hout,
                                              ushort_t* __restrict__ Bout,
                                              float* __restrict__ Fout, int N) {
    __shared__ ushort_t S[(BM + BN) * 64];
    gemm_body<MODE, BM, BN, ADDI>(S, A, BT, K, A2, BT2, K2, Xf, Pb, Rf, Hout, Bout, Fout, N,
                                  blockIdx.x, blockIdx.y);
}

extern "C" void kernel_launch(void* const* d_in, const int* in_sizes, int n_in,
                              void* d_out, int out_size, void* d_ws, size_t ws_size,
                              hipStream_t stream) {
    const float* X  = (const float*)d_in[0];  // [4096, 256, 8]
    const float* W1 = (const float*)d_in[1];  // [256, 128, 8]
    const float* W2 = (const float*)d_in[2];  // [128, 64, 8]
    const float* h1 = (const float*)d_in[3];  // [4096, 128, 8]
    const float* h2 = (const float*)d_in[4];  // [4096, 64, 8]
    float* out = (float*)d_out;

    const size_t szX  = (size_t)4096 * 2048;
    const size_t szH1 = (size_t)4096 * 1024;
    const size_t szH2 = (size_t)4096 * 512;

    float* outX = out;
    float* H1 = out + szX;
    float* H2 = H1 + szH1;

    // workspace (~79 MB; ws is ~268 MB)
    ushort_t* M1fwdA = (ushort_t*)d_ws;                 // [1024][2048]
    ushort_t* M1rbt  = M1fwdA + (size_t)1024 * 2048;    // [1024][2048]
    ushort_t* M2fwdA = M1rbt + (size_t)1024 * 2048;     // [512][1024]
    ushort_t* M2rbt  = M2fwdA + (size_t)512 * 1024;     // [512][1024]
    ushort_t* M2rneg = M2rbt + (size_t)512 * 1024;      // [512][1024]
    ushort_t* M2bt   = M2rneg + (size_t)512 * 1024;     // [1024][512]
    ushort_t* GmT1p  = M2bt + (size_t)1024 * 512;       // [1024][1024]
    ushort_t* GmT2   = GmT1p + (size_t)1024 * 1024;     // [512][512]
    ushort_t* Xb     = GmT2 + (size_t)512 * 512;        // [4096][2048]
    ushort_t* P2b    = Xb + szX;                        // [4096][1024] plain
    ushort_t* H1bA   = P2b + szH1;                      // [4096][1024]
    ushort_t* H1bB   = H1bA + szH1;
    ushort_t* H2bA   = H1bB + szH1;                     // [4096][512]
    ushort_t* H2bB   = H2bA + szH2;
    float*    R      = (float*)(H2bB + szH2);           // [4096][1024] fp32

    build_M_kernel<<<(256 * 128 * 64 + 255) / 256, 256, 0, stream>>>(
        W1, M1fwdA, M1rbt, nullptr, nullptr, 256, 128);
    build_M_kernel<<<(128 * 64 * 64 + 255) / 256, 256, 0, stream>>>(
        W2, M2fwdA, M2rbt, M2rneg, M2bt, 128, 64);

    hipMemcpyAsync(H1, h1, szH1 * sizeof(float), hipMemcpyDeviceToDevice, stream);
    hipMemcpyAsync(H2, h2, szH2 * sizeof(float), hipMemcpyDeviceToDevice, stream);
    f2bf_swz_kernel<<<(int)((szX + 255) / 256), 256, 0, stream>>>(X, Xb, (int)szX, 11);
    f2bf_swz_kernel<<<(int)((szH1 + 255) / 256), 256, 0, stream>>>(h1, H1bA, (int)szH1, 10);
    f2bf_swz_kernel<<<(int)((szH2 + 255) / 256), 256, 0, stream>>>(h2, H2bA, (int)szH2, 9);

    // Precompute R = X@M1r (fp32), GmT1p = (M1@M1r + I)^T, GmT2 = (M2@M2r)^T
    gemm_k<1, 128, 64, false><<<dim3(16, 32), 256, 0, stream>>>(
        Xb, M1rbt, 2048, nullptr, nullptr, 0, nullptr, nullptr, nullptr, nullptr, nullptr, R, 1024);
    gemm_k<4, 64, 64, true><<<dim3(16, 16), 256, 0, stream>>>(
        M1fwdA, M1rbt, 2048, nullptr, nullptr, 0, nullptr, nullptr, nullptr, nullptr, GmT1p,
        nullptr, 1024);
    gemm_k<4, 64, 64, false><<<dim3(8, 8), 256, 0, stream>>>(
        M2fwdA, M2rbt, 1024, nullptr, nullptr, 0, nullptr, nullptr, nullptr, nullptr, GmT2,
        nullptr, 512);

    ushort_t* H1old = H1bA; ushort_t* H1new = H1bB;
    ushort_t* H2old = H2bA; ushort_t* H2new = H2bB;
    for (int it = 0; it < N_ITER; ++it) {
        // P2b = bf16(H2@M2)   [4096x1024], K=512
        gemm_k<0, 128, 64, false><<<dim3(16, 32), 256, 0, stream>>>(
            H2old, M2bt, 512, nullptr, nullptr, 0, nullptr, nullptr, nullptr, nullptr, P2b,
            nullptr, 1024);
        // H1 <- H1 - a*clip(H1@Gm1p - R - P2)   [4096x1024], K=1024
        gemm_k<2, 128, 64, false><<<dim3(16, 32), 256, 0, stream>>>(
            H1old, GmT1p, 1024, nullptr, nullptr, 0, H1, P2b, R, H1, H1new, nullptr, 1024);
        // H2 <- H2 - a*clip(H2@Gm2 - H1new@M2r)   [4096x512], K=512+1024
        gemm_k<3, 64, 64, false><<<dim3(8, 64), 256, 0, stream>>>(
            H2old, GmT2, 512, H1new, M2rneg, 1024, H2, nullptr, nullptr, H2, H2new, nullptr, 512);
        ushort_t* tmp;
        tmp = H1old; H1old = H1new; H1new = tmp;
        tmp = H2old; H2old = H2new; H2new = tmp;
    }

    // x passes through unchanged
    hipMemcpyAsync(outX, X, szX * sizeof(float), hipMemcpyDeviceToDevice, stream);
}

// Round 7
// 1220.972 us; speedup vs baseline: 1.9998x; 1.0893x over previous
//
#include <hip/hip_runtime.h>

#define N_ITER 20
#define ALPHA 0.01f

typedef unsigned short ushort_t;
typedef __attribute__((ext_vector_type(8))) short bf16x8;
typedef __attribute__((ext_vector_type(16))) float f32x16;

__device__ __forceinline__ float csign(int a, int b) {
    int s = 0;
    for (int aa = a >> 1; aa; aa >>= 1) s += __popc(aa & b);
    return (s & 1) ? -1.0f : 1.0f;
}

__device__ __forceinline__ float revsign(int b) {
    int k = __popc(b);
    return ((k * (k - 1) / 2) & 1) ? -1.0f : 1.0f;
}

__device__ __forceinline__ ushort_t f2bf(float f) {
    union { float f; unsigned u; } v;
    v.f = f;
    unsigned r = v.u + 0x7fffu + ((v.u >> 16) & 1u);  // RNE; inputs finite
    return (ushort_t)(r >> 16);
}

// Swizzled storage for logical (r, k) in an [R][K] bf16 operand buffer.
// Within each 64-elem k-group (128 B), 16B block j lives at j ^ (r&7).
// Verbatim LDS staging; fragment ds_read_b128 conflict-free (round-6 verified).
__device__ __forceinline__ size_t swz64(int r, int k, int K) {
    return (size_t)r * K + (k & ~63) + ((((k >> 3) ^ r) & 7) << 3) + (k & 7);
}

__device__ __forceinline__ void async16(const void* g, void* l) {
    __builtin_amdgcn_global_load_lds((const __attribute__((address_space(1))) void*)g,
                                     (__attribute__((address_space(3))) void*)l, 16, 0, 0);
}

// Build bf16 swz64 GP matrices from W [P, Q, 8]:
//  MfA    [Q8][P8]: forward GP, A-layout    MfA[q8+a][p8+c]    = s*w
//  Mrbt   [Q8][P8]: reverse GP, B^T layout  Mrbt[q8+c][p8+a]   = s*rev*w
//  Mrneg  [Q8][P8]: -Mrbt
//  Mbtneg [P8][Q8]: -forward GP, B^T layout Mbtneg[p8+c][q8+a] = -s*w
__global__ void build_M_kernel(const float* __restrict__ W, ushort_t* __restrict__ MfA,
                               ushort_t* __restrict__ Mrbt, ushort_t* __restrict__ Mrneg,
                               ushort_t* __restrict__ Mbtneg, int P, int Q) {
    int idx = blockIdx.x * blockDim.x + threadIdx.x;
    int total = P * Q * 64;
    if (idx >= total) return;
    int c = idx & 7;
    int a = (idx >> 3) & 7;
    int pq = idx >> 6;
    int q = pq % Q;
    int p = pq / Q;
    int b = a ^ c;
    float w = W[((size_t)p * Q + q) * 8 + b];
    float fw = csign(a, b) * w;
    float rw = csign(a, b) * revsign(b) * w;
    MfA[swz64(q * 8 + a, p * 8 + c, P * 8)] = f2bf(fw);
    Mrbt[swz64(q * 8 + c, p * 8 + a, P * 8)] = f2bf(rw);
    if (Mrneg) Mrneg[swz64(q * 8 + c, p * 8 + a, P * 8)] = f2bf(-rw);
    if (Mbtneg) Mbtneg[swz64(p * 8 + c, q * 8 + a, Q * 8)] = f2bf(-fw);
}

// fp32 [R][K] plain -> bf16 swz64
__global__ void f2bf_swz_kernel(const float* __restrict__ in, ushort_t* __restrict__ out,
                                int n, int kshift) {
    int i = blockIdx.x * blockDim.x + threadIdx.x;
    if (i >= n) return;
    int K = 1 << kshift;
    int r = i >> kshift;
    int k = i & (K - 1);
    out[swz64(r, k, K)] = f2bf(in[i]);
}

// MFMA bf16 GEMM body. BMxBN block, BK=64, single LDS buffer, 256 threads (4 waves 2x2),
// wave tile (BM/2)x(BN/2) of 32x32x16 MFMAs. Optional second accumulation phase.
// MODE 1: Fout fp32 = acc                                       (R precompute)
// MODE 2: g=clip(acc - Rf); hn=Xf - a*g; Hout=hn fp32; Bout=swz64(hn)   (H1 update)
// MODE 3: g=clip(acc);      hn=Xf - a*g; Hout=hn fp32; Bout=swz64(hn)   (H2 update)
// MODE 4: Bout[swz64(col,row,N)] = bf16(acc + (ADDI && row==col))       (GmT build)
template <int MODE, int BM, int BN, bool ADDI>
__device__ __forceinline__ void gemm_body(ushort_t* __restrict__ S,
                                          const ushort_t* __restrict__ A,
                                          const ushort_t* __restrict__ BT, int K,
                                          const ushort_t* __restrict__ A2,
                                          const ushort_t* __restrict__ BT2, int K2,
                                          const float* __restrict__ Xf,
                                          const float* __restrict__ Rf,
                                          float* __restrict__ Hout,
                                          ushort_t* __restrict__ Bout,
                                          float* __restrict__ Fout,
                                          int N, int bx, int by) {
    constexpr int FI = BM / 64;
    constexpr int FJ = BN / 64;
    constexpr int CPW = (BM + BN) / 32;  // 1KB chunks (8 rows x 64 elems) per wave

    const int t = threadIdx.x;
    const int lane = t & 63;
    const int w = t >> 6;
    const int wr = w >> 1;
    const int wc = w & 1;
    const int l31 = lane & 31;
    const int lh = lane >> 5;
    const int row0 = by * BM;
    const int col0 = bx * BN;
    const int srow = lane >> 3;
    const int sk = (lane & 7) * 8;
    const int sw7 = l31 & 7;

    f32x16 acc[FI][FJ];
#pragma unroll
    for (int i = 0; i < FI; ++i)
#pragma unroll
        for (int j = 0; j < FJ; ++j)
#pragma unroll
            for (int r = 0; r < 16; ++r) acc[i][j][r] = 0.0f;

    for (int ph = 0; ph < 2; ++ph) {
        const ushort_t* Ap = ph ? A2 : A;
        const ushort_t* Bp = ph ? BT2 : BT;
        const int Kp = ph ? K2 : K;
        if (Kp == 0) break;

        const ushort_t* gp[CPW];
        int lofs[CPW];
#pragma unroll
        for (int cc = 0; cc < CPW; ++cc) {
            int ch = cc * 4 + w;
            int r8 = ch * 8;
            if (r8 < BM) {
                gp[cc] = Ap + (size_t)(row0 + r8 + srow) * Kp + sk;
            } else {
                gp[cc] = Bp + (size_t)(col0 + r8 - BM + srow) * Kp + sk;
            }
            lofs[cc] = ch * 512;
        }

        const int T = Kp >> 6;
        for (int tt = 0; tt < T; ++tt) {
#pragma unroll
            for (int cc = 0; cc < CPW; ++cc) {
                async16(gp[cc], &S[lofs[cc]]);
                gp[cc] += 64;
            }
            __syncthreads();
            bf16x8 af[4][FI], bfm[4][FJ];
#pragma unroll
            for (int s = 0; s < 4; ++s) {
                int pos = ((2 * s + lh) ^ sw7) * 8;
#pragma unroll
                for (int i = 0; i < FI; ++i)
                    af[s][i] = *(const bf16x8*)&S[(wr * (BM / 2) + i * 32 + l31) * 64 + pos];
#pragma unroll
                for (int j = 0; j < FJ; ++j)
                    bfm[s][j] = *(const bf16x8*)&S[(BM + wc * (BN / 2) + j * 32 + l31) * 64 + pos];
            }
#pragma unroll
            for (int s = 0; s < 4; ++s)
#pragma unroll
                for (int i = 0; i < FI; ++i)
#pragma unroll
                    for (int j = 0; j < FJ; ++j)
                        acc[i][j] = __builtin_amdgcn_mfma_f32_32x32x16_bf16(af[s][i], bfm[s][j],
                                                                            acc[i][j], 0, 0, 0);
            __syncthreads();
        }
    }

    // epilogue: C/D layout col=lane&31, row=(reg&3)+8*(reg>>2)+4*(lane>>5)
#pragma unroll
    for (int i = 0; i < FI; ++i) {
#pragma unroll
        for (int j = 0; j < FJ; ++j) {
#pragma unroll
            for (int r = 0; r < 16; ++r) {
                int row = row0 + wr * (BM / 2) + i * 32 + (r & 3) + 8 * (r >> 2) + 4 * lh;
                int col = col0 + wc * (BN / 2) + j * 32 + l31;
                size_t off = (size_t)row * N + col;
                float v = acc[i][j][r];
                if (MODE == 1) {
                    Fout[off] = v;
                } else if (MODE == 2) {
                    float h = Xf[off];
                    float g = fminf(fmaxf(v - Rf[off], -1.0f), 1.0f);
                    float hn = h - ALPHA * g;
                    Hout[off] = hn;
                    Bout[swz64(row, col, N)] = f2bf(hn);
                } else if (MODE == 3) {
                    float h = Xf[off];
                    float g = fminf(fmaxf(v, -1.0f), 1.0f);
                    float hn = h - ALPHA * g;
                    Hout[off] = hn;
                    Bout[swz64(row, col, N)] = f2bf(hn);
                } else {  // MODE 4 (square M==N)
                    float vv = v + ((ADDI && row == col) ? 1.0f : 0.0f);
                    Bout[swz64(col, row, N)] = f2bf(vv);
                }
            }
        }
    }
}

template <int MODE, int BM, int BN, bool ADDI>
__global__ __launch_bounds__(256) void gemm_k(const ushort_t* __restrict__ A,
                                              const ushort_t* __restrict__ BT, int K,
                                              const ushort_t* __restrict__ A2,
                                              const ushort_t* __restrict__ BT2, int K2,
                                              const float* __restrict__ Xf,
                                              const float* __restrict__ Rf,
                                              float* __restrict__ Hout,
                                              ushort_t* __restrict__ Bout,
                                              float* __restrict__ Fout, int N) {
    __shared__ ushort_t S[(BM + BN) * 64];
    gemm_body<MODE, BM, BN, ADDI>(S, A, BT, K, A2, BT2, K2, Xf, Rf, Hout, Bout, Fout, N,
                                  blockIdx.x, blockIdx.y);
}

extern "C" void kernel_launch(void* const* d_in, const int* in_sizes, int n_in,
                              void* d_out, int out_size, void* d_ws, size_t ws_size,
                              hipStream_t stream) {
    const float* X  = (const float*)d_in[0];  // [4096, 256, 8]
    const float* W1 = (const float*)d_in[1];  // [256, 128, 8]
    const float* W2 = (const float*)d_in[2];  // [128, 64, 8]
    const float* h1 = (const float*)d_in[3];  // [4096, 128, 8]
    const float* h2 = (const float*)d_in[4];  // [4096, 64, 8]
    float* out = (float*)d_out;

    const size_t szX  = (size_t)4096 * 2048;
    const size_t szH1 = (size_t)4096 * 1024;
    const size_t szH2 = (size_t)4096 * 512;

    float* outX = out;
    float* H1 = out + szX;
    float* H2 = H1 + szH1;

    // workspace (~77 MB of ~268 MB)
    ushort_t* M1fwdA  = (ushort_t*)d_ws;                 // [1024][2048]
    ushort_t* M1rbt   = M1fwdA + (size_t)1024 * 2048;    // [1024][2048]
    ushort_t* M2fwdA  = M1rbt + (size_t)1024 * 2048;     // [512][1024]
    ushort_t* M2rbt   = M2fwdA + (size_t)512 * 1024;     // [512][1024]
    ushort_t* M2rneg  = M2rbt + (size_t)512 * 1024;      // [512][1024]
    ushort_t* M2btneg = M2rneg + (size_t)512 * 1024;     // [1024][512]
    ushort_t* GmT1p   = M2btneg + (size_t)1024 * 512;    // [1024][1024]
    ushort_t* GmT2    = GmT1p + (size_t)1024 * 1024;     // [512][512]
    ushort_t* Xb      = GmT2 + (size_t)512 * 512;        // [4096][2048]
    ushort_t* H1bA    = Xb + szX;                        // [4096][1024]
    ushort_t* H1bB    = H1bA + szH1;
    ushort_t* H2bA    = H1bB + szH1;                     // [4096][512]
    ushort_t* H2bB    = H2bA + szH2;
    float*    R       = (float*)(H2bB + szH2);           // [4096][1024] fp32

    build_M_kernel<<<(256 * 128 * 64 + 255) / 256, 256, 0, stream>>>(
        W1, M1fwdA, M1rbt, nullptr, nullptr, 256, 128);
    build_M_kernel<<<(128 * 64 * 64 + 255) / 256, 256, 0, stream>>>(
        W2, M2fwdA, M2rbt, M2rneg, M2btneg, 128, 64);

    hipMemcpyAsync(H1, h1, szH1 * sizeof(float), hipMemcpyDeviceToDevice, stream);
    hipMemcpyAsync(H2, h2, szH2 * sizeof(float), hipMemcpyDeviceToDevice, stream);
    f2bf_swz_kernel<<<(int)((szX + 255) / 256), 256, 0, stream>>>(X, Xb, (int)szX, 11);
    f2bf_swz_kernel<<<(int)((szH1 + 255) / 256), 256, 0, stream>>>(h1, H1bA, (int)szH1, 10);
    f2bf_swz_kernel<<<(int)((szH2 + 255) / 256), 256, 0, stream>>>(h2, H2bA, (int)szH2, 9);

    // Precompute R = X@M1r (fp32), GmT1p = (M1@M1r + I)^T, GmT2 = (M2@M2r)^T
    gemm_k<1, 128, 64, false><<<dim3(16, 32), 256, 0, stream>>>(
        Xb, M1rbt, 2048, nullptr, nullptr, 0, nullptr, nullptr, nullptr, nullptr, R, 1024);
    gemm_k<4, 64, 64, true><<<dim3(16, 16), 256, 0, stream>>>(
        M1fwdA, M1rbt, 2048, nullptr, nullptr, 0, nullptr, nullptr, nullptr, GmT1p, nullptr, 1024);
    gemm_k<4, 64, 64, false><<<dim3(8, 8), 256, 0, stream>>>(
        M2fwdA, M2rbt, 1024, nullptr, nullptr, 0, nullptr, nullptr, nullptr, GmT2, nullptr, 512);

    ushort_t* H1old = H1bA; ushort_t* H1new = H1bB;
    ushort_t* H2old = H2bA; ushort_t* H2new = H2bB;
    for (int it = 0; it < N_ITER; ++it) {
        // A: H1 <- H1 - a*clip(H1@Gm1p - H2@M2 - R)   [4096x1024], K=1024+512
        gemm_k<2, 128, 64, false><<<dim3(16, 32), 256, 0, stream>>>(
            H1old, GmT1p, 1024, H2old, M2btneg, 512, H1, R, H1, H1new, nullptr, 1024);
        // B: H2 <- H2 - a*clip(H2@Gm2 - H1new@M2r)    [4096x512],  K=512+1024
        gemm_k<3, 64, 64, false><<<dim3(8, 64), 256, 0, stream>>>(
            H2old, GmT2, 512, H1new, M2rneg, 1024, H2, nullptr, H2, H2new, nullptr, 512);
        ushort_t* tmp;
        tmp = H1old; H1old = H1new; H1new = tmp;
        tmp = H2old; H2old = H2new; H2new = tmp;
    }

    // x passes through unchanged
    hipMemcpyAsync(outX, X, szX * sizeof(float), hipMemcpyDeviceToDevice, stream);
}